// Round 3
// baseline (226.023 us; speedup 1.0000x reference)
//
#include <hip/hip_runtime.h>
#include <math.h>

#define NB 2
#define NP 1200
#define NF 1000
#define IH 128
#define IW 128
#define TH 512
#define TW 512

#define TILE 8              // 8x8 pixel tiles
#define TX 16               // tiles per row  (IW/TILE)
#define TY 16               // tiles per col  (IH/TILE)
#define NTILE (TX*TY)       // 256 tiles per batch
#define CAP 1024            // per-tile list capacity (>= NF -> no overflow)

// ws layout
#define FD_OFF   0
#define FD_BYTES (NB*NF*64)              // 128000
#define CNT_OFF  FD_BYTES                // 512 ints = 2048 B
#define CNT_BYTES (NB*NTILE*4)
#define LST_OFF  (CNT_OFF + CNT_BYTES)   // 130048
// lists: NB*NTILE*CAP ints = 2 MB

// 64-byte per-face record: c[9], z[3], front, pads
struct __align__(16) FaceC {
    float c[9];
    float z[3];
    float front;
    float pad0, pad1, pad2;
};

__global__ void prep_kernel(const float* __restrict__ points,
                            const int*  __restrict__ faces,
                            const float* __restrict__ rot,
                            const float* __restrict__ cpos,
                            const float* __restrict__ proj,
                            float* __restrict__ normal_out,
                            FaceC* __restrict__ fdata,
                            int* __restrict__ counts,
                            int* __restrict__ lists)
{
#pragma clang fp contract(off)
    int t = blockIdx.x * blockDim.x + threadIdx.x;
    if (t >= NB * NF) return;
    int b = t / NF;
    int f = t - b * NF;
    const float* R = rot + b * 9;
    float ccx = cpos[b*3+0], ccy = cpos[b*3+1], ccz = cpos[b*3+2];
    float pr0 = proj[0], pr1 = proj[1], pr2 = proj[2];

    float q[3][3];
    float sx[3], sy[3];
    for (int k = 0; k < 3; ++k) {
        int vi = faces[f*3 + k];
        const float* P = points + (b*NP + vi) * 3;
        float vx = P[0] - ccx, vy = P[1] - ccy, vz = P[2] - ccz;
        float q0 = (vx*R[0] + vy*R[1]) + vz*R[2];
        float q1 = (vx*R[3] + vy*R[4]) + vz*R[5];
        float q2 = (vx*R[6] + vy*R[7]) + vz*R[8];
        q[k][0] = q0; q[k][1] = q1; q[k][2] = q2;
        sx[k] = (q0*pr0) / (q2*pr2);   // IEEE divide, reference order
        sy[k] = (q1*pr1) / (q2*pr2);
    }

    FaceC fd;
    float x0 = sx[0], y0 = sy[0];
    float x1 = sx[1], y1 = sy[1];
    float x2 = sx[2], y2 = sy[2];
    fd.c[0] = y1 - y2;  fd.c[1] = x2 - x1;  fd.c[2] = x1*y2 - x2*y1;
    fd.c[3] = y2 - y0;  fd.c[4] = x0 - x2;  fd.c[5] = x2*y0 - x0*y2;
    fd.c[6] = y0 - y1;  fd.c[7] = x1 - x0;  fd.c[8] = x0*y1 - x1*y0;
    fd.z[0] = q[0][2]; fd.z[1] = q[1][2]; fd.z[2] = q[2][2];

    float e1x = q[1][0]-q[0][0], e1y = q[1][1]-q[0][1], e1z = q[1][2]-q[0][2];
    float e2x = q[2][0]-q[0][0], e2y = q[2][1]-q[0][1], e2z = q[2][2]-q[0][2];
    float nx = e1y*e2z - e1z*e2y;
    float ny = e1z*e2x - e1x*e2z;
    float nz = e1x*e2y - e1y*e2x;
    fd.front = (nz > 0.0f) ? 1.0f : 0.0f;
    float nlen = sqrtf(((nx*nx + ny*ny) + nz*nz) + 1e-8f);
    float nd = nlen + 1e-15f;
    normal_out[t*3+0] = nx / nd;
    normal_out[t*3+1] = ny / nd;
    normal_out[t*3+2] = nz / nd;
    fd.pad0 = fd.pad1 = fd.pad2 = 0.0f;
    fdata[t] = fd;

    // ---- binning (front faces only; back faces are dead for both outputs) ----
    if (fd.front <= 0.0f) return;

    int tx0, tx1, ty0, ty1;
    float A2 = (x1-x0)*(y2-y0) - (x2-x0)*(y1-y0);   // 2*signed screen area
    if (fabsf(A2) < 1e-6f) {
        // near-degenerate: w/den noise can matter along the whole line; bin everywhere
        tx0 = 0; ty0 = 0; tx1 = TX-1; ty1 = TY-1;
    } else {
        // {min bary >= -delta} == triangle scaled by (1+3*delta) about centroid.
        // delta = 0.3 -> culled faces contribute <= sigmoid(-15) ~ 3e-7 to improb.
        const float s = 1.9f;
        float cx = (x0 + x1 + x2) * (1.0f/3.0f);
        float cy = (y0 + y1 + y2) * (1.0f/3.0f);
        float xa = cx + s*(x0-cx), xb = cx + s*(x1-cx), xc = cx + s*(x2-cx);
        float ya = cy + s*(y0-cy), yb = cy + s*(y1-cy), yc = cy + s*(y2-cy);
        float xmin = fminf(fminf(xa,xb),xc), xmax = fmaxf(fmaxf(xa,xb),xc);
        float ymin = fminf(fminf(ya,yb),yc), ymax = fmaxf(fmaxf(ya,yb),yc);
        // NDC -> pixel index space (+1px safety for fp rounding)
        float pxmin = (xmin + 1.0f) * (IW*0.5f) - 0.5f - 1.0f;
        float pxmax = (xmax + 1.0f) * (IW*0.5f) - 0.5f + 1.0f;
        float pymin = (1.0f - ymax) * (IH*0.5f) - 0.5f - 1.0f;
        float pymax = (1.0f - ymin) * (IH*0.5f) - 0.5f + 1.0f;
        if (pxmax < 0.0f || pymax < 0.0f || pxmin > (IW-1) || pymin > (IH-1)) return;
        int ix0 = (int)fmaxf(floorf(pxmin), 0.0f);
        int iy0 = (int)fmaxf(floorf(pymin), 0.0f);
        int ix1 = (int)fminf(ceilf(pxmax), (float)(IW-1));
        int iy1 = (int)fminf(ceilf(pymax), (float)(IH-1));
        tx0 = ix0 >> 3; tx1 = ix1 >> 3;
        ty0 = iy0 >> 3; ty1 = iy1 >> 3;
    }
    for (int ty = ty0; ty <= ty1; ++ty)
        for (int tx = tx0; tx <= tx1; ++tx) {
            int tile = b * NTILE + ty * TX + tx;
            int pos = atomicAdd(&counts[tile], 1);
            lists[tile * CAP + pos] = f;
        }
}

__global__ __launch_bounds__(64) void raster_kernel(
        const FaceC* __restrict__ fdata,
        const int*  __restrict__ counts,
        const int*  __restrict__ lists,
        const float* __restrict__ tex,
        const float* __restrict__ uvp,
        const int*  __restrict__ ft,
        float* __restrict__ imrender,
        float* __restrict__ improb)
{
#pragma clang fp contract(off)
    int b    = blockIdx.x >> 8;
    int tile = blockIdx.x & (NTILE - 1);
    int lane = threadIdx.x;
    int tx = tile & (TX - 1), ty = tile >> 4;
    int px_i = (tx << 3) | (lane & 7);
    int py_i = (ty << 3) | (lane >> 3);
    float px = (px_i + 0.5f) / (float)IW * 2.0f - 1.0f;
    float py = 1.0f - (py_i + 0.5f) / (float)IH * 2.0f;

    int cnt = counts[b * NTILE + tile];
    const int* list = lists + (size_t)(b * NTILE + tile) * CAP;
    const FaceC* fb = fdata + b * NF;

    float zmin = INFINITY;
    int fsel = 0x7fffffff;
    float b0s = 0.0f, b1s = 0.0f, b2s = 0.0f;
    bool covered = false;
    float maxd = -INFINITY;

    for (int j = 0; j < cnt; ++j) {
        int fidx = list[j];                       // wave-uniform -> scalar load
        const float* F_ = (const float*)(fb + fidx);
        float w0 = (F_[0]*px + F_[1]*py) + F_[2];
        float w1 = (F_[3]*px + F_[4]*py) + F_[5];
        float w2 = (F_[6]*px + F_[7]*py) + F_[8];
        float den = (w0 + w1) + w2;
        den = den + ((den >= 0.0f) ? 1e-8f : -1e-8f);
        bool sp = den > 0.0f;
        float mn = fminf(fminf(w0, w1), w2);
        float mx = fmaxf(fmaxf(w0, w1), w2);
        float wsel = sp ? mn : mx;
        // fast rcp: only feeds max->sigmoid; 1-ulp error is far below threshold
        float dmin = wsel * __builtin_amdgcn_rcpf(den);
        maxd = fmaxf(maxd, dmin);                 // all binned faces are front
        bool inside = sp ? (w0 >= 0.0f && w1 >= 0.0f && w2 >= 0.0f)
                         : (w0 <= 0.0f && w1 <= 0.0f && w2 <= 0.0f);
        if (inside) {
            float b0 = w0 / den, b1 = w1 / den, b2 = w2 / den;   // IEEE (ref path)
            float z = (b0*F_[9] + b1*F_[10]) + b2*F_[11];
            // strict argmin with first-index tie-break (list order is nondeterministic)
            if (z < zmin || (z == zmin && fidx < fsel)) {
                zmin = z; fsel = fidx;
                b0s = b0; b1s = b1; b2s = b2;
                covered = true;
            }
        }
    }

    // interpolated features of selected face
    float u = 0.0f, v = 0.0f, m = 0.0f;
    if (covered) {
        int j0 = ft[fsel*3+0], j1 = ft[fsel*3+1], j2 = ft[fsel*3+2];
        const float* ub = uvp + (size_t)b * NP * 2;
        u = (b0s*ub[j0*2+0] + b1s*ub[j1*2+0]) + b2s*ub[j2*2+0];
        v = (b0s*ub[j0*2+1] + b1s*ub[j1*2+1]) + b2s*ub[j2*2+1];
        m = (b0s + b1s) + b2s;
    }

    // fragment shader: g = remainder(uv,1)*2-1, gy negated; nearest grid_sample
    float gu = (u - floorf(u)) * 2.0f - 1.0f;
    float gv = (v - floorf(v)) * 2.0f - 1.0f;
    gv = -gv;
    float ix = ((gu + 1.0f) * (float)TW - 1.0f) * 0.5f;
    float iy = ((gv + 1.0f) * (float)TH - 1.0f) * 0.5f;
    float ixr = rintf(ix);
    float iyr = rintf(iy);
    int ixn = (int)ixr, iyn = (int)iyr;
    bool tvalid = (ixn >= 0) && (ixn < TW) && (iyn >= 0) && (iyn < TH);
    int ixc = min(max(ixn, 0), TW-1);
    int iyc = min(max(iyn, 0), TH-1);
    float vmul = tvalid ? 1.0f : 0.0f;
    const float* tb = tex + (size_t)b * 3 * TH * TW;
    float tr  = tb[(0*TH + iyc)*TW + ixc] * vmul;
    float tg  = tb[(1*TH + iyc)*TW + ixc] * vmul;
    float tb2 = tb[(2*TH + iyc)*TW + ixc] * vmul;

    float o0 = fminf(fmaxf(tr  * m, 0.0f), 1.0f);
    float o1 = fminf(fmaxf(tg  * m, 0.0f), 1.0f);
    float o2 = fminf(fmaxf(tb2 * m, 0.0f), 1.0f);

    float pr = 0.0f;
    if (cnt > 0) {
        float sxv = maxd / 0.02f;
        if (sxv >= 0.0f) pr = 1.0f / (1.0f + expf(-sxv));
        else { float e = expf(sxv); pr = e / (1.0f + e); }
    }

    int pix = b * (IH*IW) + py_i * IW + px_i;
    float* outp = imrender + (size_t)pix * 3;
    outp[0] = o0; outp[1] = o1; outp[2] = o2;
    improb[pix] = pr;
}

extern "C" void kernel_launch(void* const* d_in, const int* in_sizes, int n_in,
                              void* d_out, int out_size, void* d_ws, size_t ws_size,
                              hipStream_t stream) {
    const float* points = (const float*)d_in[0];
    const int*   faces  = (const int*)  d_in[1];
    const float* rot    = (const float*)d_in[2];
    const float* cpos   = (const float*)d_in[3];
    const float* proj   = (const float*)d_in[4];
    const float* uvp    = (const float*)d_in[5];
    const float* tex    = (const float*)d_in[6];
    const int*   ft     = (const int*)  d_in[7];

    float* out        = (float*)d_out;
    float* imrender   = out;
    float* improb     = out + NB*IH*IW*3;
    float* normal_out = out + NB*IH*IW*3 + NB*IH*IW;

    char*  ws     = (char*)d_ws;
    FaceC* fdata  = (FaceC*)(ws + FD_OFF);
    int*   counts = (int*)  (ws + CNT_OFF);
    int*   lists  = (int*)  (ws + LST_OFF);

    hipMemsetAsync(counts, 0, CNT_BYTES, stream);
    prep_kernel<<<(NB*NF + 255)/256, 256, 0, stream>>>(
        points, faces, rot, cpos, proj, normal_out, fdata, counts, lists);
    raster_kernel<<<NB*NTILE, 64, 0, stream>>>(
        fdata, counts, lists, tex, uvp, ft, imrender, improb);
}

// Round 4
// 77.412 us; speedup vs baseline: 2.9198x; 2.9198x over previous
//
#include <hip/hip_runtime.h>
#include <math.h>

#define NB 2
#define NP 1200
#define NF 1000
#define IH 128
#define IW 128
#define TH 512
#define TW 512

#define TILE 8              // 8x8 pixel tiles
#define TX 16               // tiles per row  (IW/TILE)
#define TY 16               // tiles per col  (IH/TILE)
#define NTILE (TX*TY)       // 256 tiles per batch
#define CAP 1024            // per-tile list capacity (>= NF -> no overflow)

#define TPB 512             // 8 waves per raster block
#define NGRP 8
#define FCHUNK 256          // faces staged to LDS per chunk

// ws layout
#define FD_OFF   0
#define FD_BYTES (NB*NF*64)              // 128000
#define CNT_OFF  FD_BYTES
#define CNT_BYTES (NB*NTILE*4)           // 2048
#define LST_OFF  (CNT_OFF + CNT_BYTES)
// lists: NB*NTILE*CAP ints = 2 MB

// 64-byte per-face record: c[9], z[3], front, pads
struct __align__(16) FaceC {
    float c[9];
    float z[3];
    float front;
    float pad0, pad1, pad2;
};

__global__ void prep_kernel(const float* __restrict__ points,
                            const int*  __restrict__ faces,
                            const float* __restrict__ rot,
                            const float* __restrict__ cpos,
                            const float* __restrict__ proj,
                            float* __restrict__ normal_out,
                            FaceC* __restrict__ fdata,
                            int* __restrict__ counts,
                            int* __restrict__ lists)
{
#pragma clang fp contract(off)
    int t = blockIdx.x * blockDim.x + threadIdx.x;
    if (t >= NB * NF) return;
    int b = t / NF;
    int f = t - b * NF;
    const float* R = rot + b * 9;
    float ccx = cpos[b*3+0], ccy = cpos[b*3+1], ccz = cpos[b*3+2];
    float pr0 = proj[0], pr1 = proj[1], pr2 = proj[2];

    float q[3][3];
    float sx[3], sy[3];
    for (int k = 0; k < 3; ++k) {
        int vi = faces[f*3 + k];
        const float* P = points + (b*NP + vi) * 3;
        float vx = P[0] - ccx, vy = P[1] - ccy, vz = P[2] - ccz;
        float q0 = (vx*R[0] + vy*R[1]) + vz*R[2];
        float q1 = (vx*R[3] + vy*R[4]) + vz*R[5];
        float q2 = (vx*R[6] + vy*R[7]) + vz*R[8];
        q[k][0] = q0; q[k][1] = q1; q[k][2] = q2;
        sx[k] = (q0*pr0) / (q2*pr2);   // IEEE divide, reference order
        sy[k] = (q1*pr1) / (q2*pr2);
    }

    FaceC fd;
    float x0 = sx[0], y0 = sy[0];
    float x1 = sx[1], y1 = sy[1];
    float x2 = sx[2], y2 = sy[2];
    fd.c[0] = y1 - y2;  fd.c[1] = x2 - x1;  fd.c[2] = x1*y2 - x2*y1;
    fd.c[3] = y2 - y0;  fd.c[4] = x0 - x2;  fd.c[5] = x2*y0 - x0*y2;
    fd.c[6] = y0 - y1;  fd.c[7] = x1 - x0;  fd.c[8] = x0*y1 - x1*y0;
    fd.z[0] = q[0][2]; fd.z[1] = q[1][2]; fd.z[2] = q[2][2];

    float e1x = q[1][0]-q[0][0], e1y = q[1][1]-q[0][1], e1z = q[1][2]-q[0][2];
    float e2x = q[2][0]-q[0][0], e2y = q[2][1]-q[0][1], e2z = q[2][2]-q[0][2];
    float nx = e1y*e2z - e1z*e2y;
    float ny = e1z*e2x - e1x*e2z;
    float nz = e1x*e2y - e1y*e2x;
    fd.front = (nz > 0.0f) ? 1.0f : 0.0f;
    float nlen = sqrtf(((nx*nx + ny*ny) + nz*nz) + 1e-8f);
    float nd = nlen + 1e-15f;
    normal_out[t*3+0] = nx / nd;
    normal_out[t*3+1] = ny / nd;
    normal_out[t*3+2] = nz / nd;
    fd.pad0 = fd.pad1 = fd.pad2 = 0.0f;
    fdata[t] = fd;

    // ---- binning (front faces only; back faces are dead for both outputs) ----
    if (fd.front <= 0.0f) return;

    int tx0, tx1, ty0, ty1;
    float A2 = (x1-x0)*(y2-y0) - (x2-x0)*(y1-y0);   // 2*signed screen area
    if (fabsf(A2) < 1e-6f) {
        // near-degenerate: w/den noise can matter along the whole line; bin everywhere
        tx0 = 0; ty0 = 0; tx1 = TX-1; ty1 = TY-1;
    } else {
        // {min bary >= -delta} == triangle scaled by (1+3*delta) about centroid.
        // delta = 0.15 -> culled faces contribute <= sigmoid(-7.5) ~ 5.5e-4 to improb.
        const float s = 1.45f;
        float cx = (x0 + x1 + x2) * (1.0f/3.0f);
        float cy = (y0 + y1 + y2) * (1.0f/3.0f);
        float xa = cx + s*(x0-cx), xb = cx + s*(x1-cx), xc = cx + s*(x2-cx);
        float ya = cy + s*(y0-cy), yb = cy + s*(y1-cy), yc = cy + s*(y2-cy);
        float xmin = fminf(fminf(xa,xb),xc), xmax = fmaxf(fmaxf(xa,xb),xc);
        float ymin = fminf(fminf(ya,yb),yc), ymax = fmaxf(fmaxf(ya,yb),yc);
        float pxmin = (xmin + 1.0f) * (IW*0.5f) - 0.5f - 1.0f;
        float pxmax = (xmax + 1.0f) * (IW*0.5f) - 0.5f + 1.0f;
        float pymin = (1.0f - ymax) * (IH*0.5f) - 0.5f - 1.0f;
        float pymax = (1.0f - ymin) * (IH*0.5f) - 0.5f + 1.0f;
        if (pxmax < 0.0f || pymax < 0.0f || pxmin > (IW-1) || pymin > (IH-1)) return;
        int ix0 = (int)fmaxf(floorf(pxmin), 0.0f);
        int iy0 = (int)fmaxf(floorf(pymin), 0.0f);
        int ix1 = (int)fminf(ceilf(pxmax), (float)(IW-1));
        int iy1 = (int)fminf(ceilf(pymax), (float)(IH-1));
        tx0 = ix0 >> 3; tx1 = ix1 >> 3;
        ty0 = iy0 >> 3; ty1 = iy1 >> 3;
    }
    for (int ty = ty0; ty <= ty1; ++ty)
        for (int tx = tx0; tx <= tx1; ++tx) {
            int tile = b * NTILE + ty * TX + tx;
            int pos = atomicAdd(&counts[tile], 1);
            lists[tile * CAP + pos] = f;
        }
}

// LDS: face chunk (FCHUNK*16 floats = 16 KB) aliased with partials (512*9 floats = 18 KB)
#define LDSF 4608

__global__ __launch_bounds__(TPB) void raster_kernel(
        const FaceC* __restrict__ fdata,
        const int*  __restrict__ counts,
        const int*  __restrict__ lists,
        const float* __restrict__ tex,
        const float* __restrict__ uvp,
        const int*  __restrict__ ft,
        float* __restrict__ imrender,
        float* __restrict__ improb)
{
#pragma clang fp contract(off)
    __shared__ __align__(16) float lds[LDSF];

    int b    = blockIdx.x >> 8;
    int tile = blockIdx.x & (NTILE - 1);
    int t = threadIdx.x;
    int g = t >> 6;           // wave / face-group id (0..7)
    int l = t & 63;           // pixel lane
    int tx = tile & (TX - 1), ty = tile >> 4;
    int px_i = (tx << 3) | (l & 7);
    int py_i = (ty << 3) | (l >> 3);
    float px = (px_i + 0.5f) / (float)IW * 2.0f - 1.0f;
    float py = 1.0f - (py_i + 0.5f) / (float)IH * 2.0f;

    int cnt = counts[b * NTILE + tile];
    const int* list = lists + (size_t)(b * NTILE + tile) * CAP;
    const FaceC* fb = fdata + b * NF;

    float zmin = INFINITY;
    int fsel = 0x7fffffff;
    float b0s = 0.0f, b1s = 0.0f, b2s = 0.0f;
    bool covered = false;
    float maxd = -INFINITY;

    for (int base = 0; base < cnt; base += FCHUNK) {
        int c = min(FCHUNK, cnt - base);
        __syncthreads();
        // cooperative gather: c faces * 4 float4 each
        for (int i = t; i < c * 4; i += TPB) {
            int fidx = list[base + (i >> 2)];
            ((float4*)lds)[i] = ((const float4*)(fb + fidx))[i & 3];
        }
        __syncthreads();

        for (int j = g; j < c; j += NGRP) {
            const float* F_ = lds + j * 16;
            float w0 = (F_[0]*px + F_[1]*py) + F_[2];
            float w1 = (F_[3]*px + F_[4]*py) + F_[5];
            float w2 = (F_[6]*px + F_[7]*py) + F_[8];
            float den = (w0 + w1) + w2;
            den = den + ((den >= 0.0f) ? 1e-8f : -1e-8f);
            bool sp = den > 0.0f;
            float mn = fminf(fminf(w0, w1), w2);
            float mx = fmaxf(fmaxf(w0, w1), w2);
            float wsel = sp ? mn : mx;
            float dmin = wsel * __builtin_amdgcn_rcpf(den);
            maxd = fmaxf(maxd, dmin);             // all binned faces are front
            bool inside = sp ? (w0 >= 0.0f && w1 >= 0.0f && w2 >= 0.0f)
                             : (w0 <= 0.0f && w1 <= 0.0f && w2 <= 0.0f);
            if (inside) {
                float b0 = w0 / den, b1 = w1 / den, b2 = w2 / den;  // IEEE (ref path)
                float z = (b0*F_[9] + b1*F_[10]) + b2*F_[11];
                int fidx = list[base + j];
                if (z < zmin || (z == zmin && fidx < fsel)) {
                    zmin = z; fsel = fidx;
                    b0s = b0; b1s = b1; b2s = b2;
                    covered = true;
                }
            }
        }
    }

    // ---- merge the 8 wave-partials via LDS (stride-9: conflict-free) ----
    __syncthreads();
    {
        float* rec = lds + t * 9;
        rec[0] = zmin;
        rec[1] = __int_as_float(fsel);
        rec[2] = b0s; rec[3] = b1s; rec[4] = b2s;
        rec[5] = maxd;
        rec[6] = __int_as_float(covered ? 1 : 0);
    }
    __syncthreads();

    if (t < 64) {
        float zb = INFINITY, rb0 = 0.0f, rb1 = 0.0f, rb2 = 0.0f;
        int fs = 0x7fffffff;
        bool cov = false;
        float md = -INFINITY;
        for (int gg = 0; gg < NGRP; ++gg) {
            const float* rec = lds + (gg * 64 + t) * 9;
            float zg = rec[0];
            int fg = __float_as_int(rec[1]);
            if (__float_as_int(rec[6]) && (zg < zb || (zg == zb && fg < fs))) {
                zb = zg; fs = fg;
                rb0 = rec[2]; rb1 = rec[3]; rb2 = rec[4];
                cov = true;
            }
            md = fmaxf(md, rec[5]);
        }

        float u = 0.0f, v = 0.0f, m = 0.0f;
        if (cov) {
            int j0 = ft[fs*3+0], j1 = ft[fs*3+1], j2 = ft[fs*3+2];
            const float* ub = uvp + (size_t)b * NP * 2;
            u = (rb0*ub[j0*2+0] + rb1*ub[j1*2+0]) + rb2*ub[j2*2+0];
            v = (rb0*ub[j0*2+1] + rb1*ub[j1*2+1]) + rb2*ub[j2*2+1];
            m = (rb0 + rb1) + rb2;
        }

        float gu = (u - floorf(u)) * 2.0f - 1.0f;
        float gv = (v - floorf(v)) * 2.0f - 1.0f;
        gv = -gv;
        float ix = ((gu + 1.0f) * (float)TW - 1.0f) * 0.5f;
        float iy = ((gv + 1.0f) * (float)TH - 1.0f) * 0.5f;
        float ixr = rintf(ix);
        float iyr = rintf(iy);
        int ixn = (int)ixr, iyn = (int)iyr;
        bool tvalid = (ixn >= 0) && (ixn < TW) && (iyn >= 0) && (iyn < TH);
        int ixc = min(max(ixn, 0), TW-1);
        int iyc = min(max(iyn, 0), TH-1);
        float vmul = tvalid ? 1.0f : 0.0f;
        const float* tb = tex + (size_t)b * 3 * TH * TW;
        float tr  = tb[(0*TH + iyc)*TW + ixc] * vmul;
        float tg  = tb[(1*TH + iyc)*TW + ixc] * vmul;
        float tb2 = tb[(2*TH + iyc)*TW + ixc] * vmul;

        float o0 = fminf(fmaxf(tr  * m, 0.0f), 1.0f);
        float o1 = fminf(fmaxf(tg  * m, 0.0f), 1.0f);
        float o2 = fminf(fmaxf(tb2 * m, 0.0f), 1.0f);

        float pr = 0.0f;
        if (cnt > 0) {
            float sxv = md / 0.02f;
            if (sxv >= 0.0f) pr = 1.0f / (1.0f + expf(-sxv));
            else { float e = expf(sxv); pr = e / (1.0f + e); }
        }

        int ppx = (tx << 3) | (t & 7);
        int ppy = (ty << 3) | (t >> 3);
        int pix = b * (IH*IW) + ppy * IW + ppx;
        float* outp = imrender + (size_t)pix * 3;
        outp[0] = o0; outp[1] = o1; outp[2] = o2;
        improb[pix] = pr;
    }
}

extern "C" void kernel_launch(void* const* d_in, const int* in_sizes, int n_in,
                              void* d_out, int out_size, void* d_ws, size_t ws_size,
                              hipStream_t stream) {
    const float* points = (const float*)d_in[0];
    const int*   faces  = (const int*)  d_in[1];
    const float* rot    = (const float*)d_in[2];
    const float* cpos   = (const float*)d_in[3];
    const float* proj   = (const float*)d_in[4];
    const float* uvp    = (const float*)d_in[5];
    const float* tex    = (const float*)d_in[6];
    const int*   ft     = (const int*)  d_in[7];

    float* out        = (float*)d_out;
    float* imrender   = out;
    float* improb     = out + NB*IH*IW*3;
    float* normal_out = out + NB*IH*IW*3 + NB*IH*IW;

    char*  ws     = (char*)d_ws;
    FaceC* fdata  = (FaceC*)(ws + FD_OFF);
    int*   counts = (int*)  (ws + CNT_OFF);
    int*   lists  = (int*)  (ws + LST_OFF);

    hipMemsetAsync(counts, 0, CNT_BYTES, stream);
    prep_kernel<<<(NB*NF + 255)/256, 256, 0, stream>>>(
        points, faces, rot, cpos, proj, normal_out, fdata, counts, lists);
    raster_kernel<<<NB*NTILE, TPB, 0, stream>>>(
        fdata, counts, lists, tex, uvp, ft, imrender, improb);
}